// Round 1
// baseline (1077.531 us; speedup 1.0000x reference)
//
#include <hip/hip_runtime.h>

#define E_EDGES 1000000
#define N_NODES 100000
#define HID 128

// ---- workspace layout (bytes) ----
// 0    : counts[8]  (int)   -- per-combo edge counts (memset 0)
// 32   : cursor[8]  (int)   -- scatter cursors       (memset 0)
// 64   : seg[8]     (int)   -- padded segment starts (edges)
// 96   : tile[8]    (int)   -- segment starts in 64-edge tiles; tile[6]=total
// 256  : cmb[E]     (int8)  -- combo id per edge (-1 invalid)
// WS_LIST : list[E + 6*64] (int) -- bucketed edge ids, pad slots = -1 (memset 0xFF)
// WS_W1F  : w1 bf16 frags  6*12*8*64*8
// WS_W2F  : w2 bf16 frags  6*4*8*64*8
static constexpr int    WS_CMB  = 256;
static constexpr int    WS_LIST = 1000448;
static constexpr int    WS_W1F  = 5001984;   // 1000448 + 1000384*4 = 5001984 (256-aligned)
static constexpr int    WS_W2F  = 5591808;   // + 294912*2
// end = 5788416 bytes (~5.8 MB)

typedef __bf16 bf16x8 __attribute__((ext_vector_type(8)));
typedef float  f32x4  __attribute__((ext_vector_type(4)));

__device__ __forceinline__ unsigned short f2bf(float f) {
    unsigned int u = __builtin_bit_cast(unsigned int, f);
    u = (u + 0x7FFFu + ((u >> 16) & 1u)) >> 16;   // RNE
    return (unsigned short)u;
}

// ---------------- weight conversion: fp32 -> bf16 MFMA B-frag layout ----------------
// w1f flat idx: ((c*12+kt)*8+nt)*64*8 + lane*8 + j  ; element = W[k=kt*32+(lane>>4)*8+j][n=nt*16+(lane&15)]
__global__ void k_wconv(const float* __restrict__ W1, const float* __restrict__ W2,
                        unsigned short* __restrict__ w1f, unsigned short* __restrict__ w2f) {
    int idx = blockIdx.x * 256 + threadIdx.x;
    if (idx < 294912) {
        int j = idx & 7, lane = (idx >> 3) & 63, nt = (idx >> 9) & 7;
        int t = idx >> 12;            // 0..71
        int c = t / 12, kt = t - c * 12;
        int k = kt * 32 + ((lane >> 4) << 3) + j;
        int n = (nt << 4) + (lane & 15);
        w1f[idx] = f2bf(W1[(c * 384 + k) * 128 + n]);
    } else {
        int i2 = idx - 294912;        // < 98304
        int j = i2 & 7, lane = (i2 >> 3) & 63, nt = (i2 >> 9) & 7;
        int t = i2 >> 12;             // 0..23
        int c = t >> 2, kt = t & 3;
        int k = kt * 32 + ((lane >> 4) << 3) + j;
        int n = (nt << 4) + (lane & 15);
        w2f[i2] = f2bf(W2[(c * 128 + k) * 128 + n]);
    }
}

// ---------------- classify edges, count per combo, zero invalid outputs ----------------
__global__ void k_classify(const int* __restrict__ ei, const int* __restrict__ vol,
                           signed char* __restrict__ cmb, float* __restrict__ out,
                           int* __restrict__ counts) {
    __shared__ int bc[6];
    int tid = threadIdx.x;
    if (tid < 6) bc[tid] = 0;
    __syncthreads();
    int eid = blockIdx.x * 256 + tid;
    if (eid < E_EDGES) {
        int s = ei[eid], t = ei[E_EDGES + eid];
        int gs = vol[s] / 3, ge = vol[t] / 3;     // volume 0..8 -> group 0..2
        int cc = -1;
        if (gs <= ge) cc = (gs == 0 ? 0 : (gs == 1 ? 2 : 3)) + ge;  // (0,0)(0,1)(0,2)(1,1)(1,2)(2,2)
        cmb[eid] = (signed char)cc;
        if (cc < 0) out[eid] = 0.f;
        else atomicAdd(&bc[cc], 1);
    }
    __syncthreads();
    if (tid < 6 && bc[tid] > 0) atomicAdd(&counts[tid], bc[tid]);
}

// ---------------- segment offsets (pad each combo to multiple of 64) ----------------
__global__ void k_offsets(int* __restrict__ ws) {
    if (threadIdx.x == 0 && blockIdx.x == 0) {
        int* counts = ws;        // ints 0..7
        int* seg    = ws + 16;   // byte 64
        int* tile   = ws + 24;   // byte 96
        int acc = 0;
        for (int c = 0; c < 6; ++c) {
            seg[c]  = acc;
            tile[c] = acc >> 6;
            acc += ((counts[c] + 63) >> 6) << 6;
        }
        seg[6]  = acc;
        tile[6] = acc >> 6;      // total tiles
    }
}

// ---------------- scatter edge ids into combo buckets ----------------
__global__ void k_scatter(const signed char* __restrict__ cmb, int* __restrict__ list,
                          const int* __restrict__ seg, int* __restrict__ cursor) {
    __shared__ int bc[6], basep[6];
    int tid = threadIdx.x;
    if (tid < 6) bc[tid] = 0;
    __syncthreads();
    int eid = blockIdx.x * 256 + tid;
    int cc = -1, lp = 0;
    if (eid < E_EDGES) {
        cc = cmb[eid];
        if (cc >= 0) lp = atomicAdd(&bc[cc], 1);
    }
    __syncthreads();
    if (tid < 6) basep[tid] = bc[tid] > 0 ? atomicAdd(&cursor[tid], bc[tid]) : 0;
    __syncthreads();
    if (cc >= 0) list[seg[cc] + basep[cc] + lp] = eid;
}

// ---------------- fused MLP over one 64-edge tile of one combo ----------------
// A1 LDS tile: 64 rows x 384 cols bf16, padded row stride 392 (784B, 16B-aligned, 2-way banks only)
// h1 overlay: inside each wave's OWN 16-row A region (16*392=6272 elems >= 16*136), stride 136
__global__ __launch_bounds__(256) void k_mlp(
    const float* __restrict__ x, const int* __restrict__ ei, const float* __restrict__ efeat,
    const int* __restrict__ tile_tab, const int* __restrict__ list,
    const unsigned short* __restrict__ w1f, const unsigned short* __restrict__ w2f,
    const float* __restrict__ b1, const float* __restrict__ g1, const float* __restrict__ be1,
    const float* __restrict__ b2, const float* __restrict__ g2, const float* __restrict__ be2,
    const float* __restrict__ W3, const float* __restrict__ b3,
    float* __restrict__ out)
{
    __shared__ unsigned short Albuf[64 * 392];
    __shared__ int eids_s[64], sn[64], en[64];

    int b = blockIdx.x;
    if (b >= tile_tab[6]) return;
    int c = 0;
#pragma unroll
    for (int k = 1; k < 6; ++k) if (b >= tile_tab[k]) c = k;
    int tb = b - tile_tab[c];
    int segbase = tile_tab[c] * 64;
    int tid = threadIdx.x;

    if (tid < 64) {
        int eid = list[segbase + tb * 64 + tid];
        eids_s[tid] = eid;
        int a = 0, bb = 0;
        if (eid >= 0) { a = ei[eid]; bb = ei[E_EDGES + eid]; }
        sn[tid] = a; en[tid] = bb;
    }
    __syncthreads();

    // ---- stage A = [xs | xe | e] as bf16 ----
#pragma unroll
    for (int sec = 0; sec < 3; ++sec) {
#pragma unroll
        for (int it = 0; it < 8; ++it) {
            int i = tid + it * 256;           // 2048 float4 per section
            int r = i >> 5, c4 = i & 31;
            float4 v = make_float4(0.f, 0.f, 0.f, 0.f);
            if (eids_s[r] >= 0) {
                const float* src;
                if (sec == 0)      src = x + (long)sn[r] * 128;
                else if (sec == 1) src = x + (long)en[r] * 128;
                else               src = efeat + (long)eids_s[r] * 128;
                v = ((const float4*)src)[c4];
            }
            ushort4 u;
            u.x = f2bf(v.x); u.y = f2bf(v.y); u.z = f2bf(v.z); u.w = f2bf(v.w);
            *(ushort4*)(&Albuf[r * 392 + sec * 128 + c4 * 4]) = u;
        }
    }
    __syncthreads();

    int lane = tid & 63;
    int wv = tid >> 6;           // wave = one 16-row M-tile
    int colb = lane & 15;
    int quad = lane >> 4;

    const bf16x8* w1v = (const bf16x8*)w1f;
    const bf16x8* w2v = (const bf16x8*)w2f;
    const f32x4 zero4 = {0.f, 0.f, 0.f, 0.f};

    // ---- layer 1: [64x384] @ [384x128] ----
    f32x4 acc[8];
#pragma unroll
    for (int nt = 0; nt < 8; ++nt) acc[nt] = zero4;
    int arow = (wv * 16 + colb) * 392 + quad * 8;
#pragma unroll
    for (int kt = 0; kt < 12; ++kt) {
        bf16x8 af = *(const bf16x8*)(&Albuf[arow + kt * 32]);
        int wbase = ((c * 12 + kt) * 8) * 64 + lane;
#pragma unroll
        for (int nt = 0; nt < 8; ++nt) {
            bf16x8 bf = w1v[wbase + nt * 64];
            acc[nt] = __builtin_amdgcn_mfma_f32_16x16x32_bf16(af, bf, acc[nt], 0, 0, 0);
        }
    }

    // ---- LN1 + relu (in-register; row = quad*4+reg across the 16 lanes of a quad) ----
    float pb[8], pg[8], pe[8];
#pragma unroll
    for (int nt = 0; nt < 8; ++nt) {
        int col = c * 128 + colb + nt * 16;
        pb[nt] = b1[col]; pg[nt] = g1[col]; pe[nt] = be1[col];
    }
    float sum[4] = {0, 0, 0, 0}, sq[4] = {0, 0, 0, 0};
#pragma unroll
    for (int nt = 0; nt < 8; ++nt)
#pragma unroll
        for (int r = 0; r < 4; ++r) {
            float v = acc[nt][r] + pb[nt];
            acc[nt][r] = v;
            sum[r] += v; sq[r] += v * v;
        }
#pragma unroll
    for (int m = 1; m < 16; m <<= 1)
#pragma unroll
        for (int r = 0; r < 4; ++r) {
            sum[r] += __shfl_xor(sum[r], m);
            sq[r]  += __shfl_xor(sq[r], m);
        }
    float mean_[4], rstd_[4];
#pragma unroll
    for (int r = 0; r < 4; ++r) {
        float mu = sum[r] * 0.0078125f;
        float var = sq[r] * 0.0078125f - mu * mu;
        mean_[r] = mu;
        rstd_[r] = rsqrtf(var + 1e-5f);
    }
    // write h1 (bf16) into this wave's private LDS region, row-major stride 136
    int h1base = wv * 6272;
#pragma unroll
    for (int nt = 0; nt < 8; ++nt)
#pragma unroll
        for (int r = 0; r < 4; ++r) {
            float v = (acc[nt][r] - mean_[r]) * rstd_[r] * pg[nt] + pe[nt];
            v = fmaxf(v, 0.f);
            Albuf[h1base + (quad * 4 + r) * 136 + colb + nt * 16] = f2bf(v);
        }

    // ---- layer 2: [16x128] @ [128x128] (per wave; same-wave LDS RAW, program order) ----
    f32x4 acc2[8];
#pragma unroll
    for (int nt = 0; nt < 8; ++nt) acc2[nt] = zero4;
    int h1row = wv * 6272 + colb * 136 + quad * 8;
#pragma unroll
    for (int kt = 0; kt < 4; ++kt) {
        bf16x8 af = *(const bf16x8*)(&Albuf[h1row + kt * 32]);
        int wbase = ((c * 4 + kt) * 8) * 64 + lane;
#pragma unroll
        for (int nt = 0; nt < 8; ++nt) {
            bf16x8 bf = w2v[wbase + nt * 64];
            acc2[nt] = __builtin_amdgcn_mfma_f32_16x16x32_bf16(af, bf, acc2[nt], 0, 0, 0);
        }
    }

    // ---- LN2 + relu fused with layer 3 dot (h2 . W3) ----
#pragma unroll
    for (int nt = 0; nt < 8; ++nt) {
        int col = c * 128 + colb + nt * 16;
        pb[nt] = b2[col]; pg[nt] = g2[col]; pe[nt] = be2[col];
    }
#pragma unroll
    for (int r = 0; r < 4; ++r) { sum[r] = 0.f; sq[r] = 0.f; }
#pragma unroll
    for (int nt = 0; nt < 8; ++nt)
#pragma unroll
        for (int r = 0; r < 4; ++r) {
            float v = acc2[nt][r] + pb[nt];
            acc2[nt][r] = v;
            sum[r] += v; sq[r] += v * v;
        }
#pragma unroll
    for (int m = 1; m < 16; m <<= 1)
#pragma unroll
        for (int r = 0; r < 4; ++r) {
            sum[r] += __shfl_xor(sum[r], m);
            sq[r]  += __shfl_xor(sq[r], m);
        }
#pragma unroll
    for (int r = 0; r < 4; ++r) {
        float mu = sum[r] * 0.0078125f;
        float var = sq[r] * 0.0078125f - mu * mu;
        mean_[r] = mu;
        rstd_[r] = rsqrtf(var + 1e-5f);
    }
    float w3v[8];
#pragma unroll
    for (int nt = 0; nt < 8; ++nt) w3v[nt] = W3[c * 128 + colb + nt * 16];
    float part[4] = {0, 0, 0, 0};
#pragma unroll
    for (int nt = 0; nt < 8; ++nt)
#pragma unroll
        for (int r = 0; r < 4; ++r) {
            float v = (acc2[nt][r] - mean_[r]) * rstd_[r] * pg[nt] + pe[nt];
            v = fmaxf(v, 0.f);
            part[r] += v * w3v[nt];
        }
#pragma unroll
    for (int m = 1; m < 16; m <<= 1)
#pragma unroll
        for (int r = 0; r < 4; ++r) part[r] += __shfl_xor(part[r], m);

    float b3v = b3[c];
    if (colb == 0) {
#pragma unroll
        for (int r = 0; r < 4; ++r) {
            int eid = eids_s[wv * 16 + quad * 4 + r];
            if (eid >= 0) out[eid] = part[r] + b3v;
        }
    }
}

extern "C" void kernel_launch(void* const* d_in, const int* in_sizes, int n_in,
                              void* d_out, int out_size, void* d_ws, size_t ws_size,
                              hipStream_t stream) {
    const float* x    = (const float*)d_in[0];
    const int*   ei   = (const int*)d_in[1];
    const float* e    = (const float*)d_in[2];
    const int*   vol  = (const int*)d_in[3];
    const float* W1   = (const float*)d_in[4];
    const float* b1   = (const float*)d_in[5];
    const float* g1   = (const float*)d_in[6];
    const float* be1  = (const float*)d_in[7];
    const float* W2   = (const float*)d_in[8];
    const float* b2   = (const float*)d_in[9];
    const float* g2   = (const float*)d_in[10];
    const float* be2  = (const float*)d_in[11];
    const float* W3   = (const float*)d_in[12];
    const float* b3   = (const float*)d_in[13];
    float* out = (float*)d_out;
    char* wsb = (char*)d_ws;

    hipMemsetAsync(wsb, 0, 256, stream);                                     // counters/cursors
    hipMemsetAsync(wsb + WS_LIST, 0xFF, (E_EDGES + 384) * sizeof(int), stream); // pad slots = -1

    k_wconv<<<1536, 256, 0, stream>>>(W1, W2,
        (unsigned short*)(wsb + WS_W1F), (unsigned short*)(wsb + WS_W2F));
    k_classify<<<(E_EDGES + 255) / 256, 256, 0, stream>>>(ei, vol,
        (signed char*)(wsb + WS_CMB), out, (int*)wsb);
    k_offsets<<<1, 64, 0, stream>>>((int*)wsb);
    k_scatter<<<(E_EDGES + 255) / 256, 256, 0, stream>>>(
        (const signed char*)(wsb + WS_CMB), (int*)(wsb + WS_LIST),
        (const int*)(wsb + 64), (int*)(wsb + 32));
    k_mlp<<<E_EDGES / 64 + 6, 256, 0, stream>>>(
        x, ei, e, (const int*)(wsb + 96), (const int*)(wsb + WS_LIST),
        (const unsigned short*)(wsb + WS_W1F), (const unsigned short*)(wsb + WS_W2F),
        b1, g1, be1, b2, g2, be2, W3, b3, out);
}